// Round 11
// baseline (3005.795 us; speedup 1.0000x reference)
//
#include <hip/hip_runtime.h>
#include <stdint.h>

// Problem constants (B,F,S,H) = (256, 2, 256, 128)
#define BB 256
#define SS 256
#define HH 128
#define NT 512
#define CHUNK 8
#define GLD 132   // G_T row stride in floats: 33 x 16B granules, 33 % 32 == 1
#define NEG_INF (-3.402823466e+38f)

#define JAX_PARTITIONABLE 1
#define TOURS_AS_INT 0

// NOTE (validated r4/r5): accumulation ORDER in every dot product that feeds
// the trajectory (gates, w3h, E-scores) is load-bearing — bit-identical
// orders give absmax 0.0078125 with zero tour flips. r6 changes are thread
// MAPPING + the G2 exp-sum order (pure-output logp, ulp-level, no feedback).

// ---------------- threefry-2x32 (exact JAX rotation/injection schedule) -----
__device__ __forceinline__ void tf2x32(unsigned int k0, unsigned int k1,
                                       unsigned int x0, unsigned int x1,
                                       unsigned int& o0, unsigned int& o1) {
  unsigned int k2 = k0 ^ k1 ^ 0x1BD11BDAu;
  x0 += k0; x1 += k1;
#define TFR(r) { x0 += x1; x1 = (x1 << (r)) | (x1 >> (32 - (r))); x1 ^= x0; }
  TFR(13) TFR(15) TFR(26) TFR(6)
  x0 += k1; x1 += k2 + 1u;
  TFR(17) TFR(29) TFR(16) TFR(24)
  x0 += k2; x1 += k0 + 2u;
  TFR(13) TFR(15) TFR(26) TFR(6)
  x0 += k0; x1 += k1 + 3u;
  TFR(17) TFR(29) TFR(16) TFR(24)
  x0 += k1; x1 += k2 + 4u;
  TFR(13) TFR(15) TFR(26) TFR(6)
  x0 += k2; x1 += k0 + 5u;
#undef TFR
  o0 = x0; o1 = x1;
}

__device__ __forceinline__ float gumbel_from_bits(unsigned int bits) {
  unsigned int fb = (bits >> 9) | 0x3f800000u;
  float f = __uint_as_float(fb) - 1.0f;   // [0,1)
  f = (f == 0.0f) ? 1.17549435e-38f : f;
  return -logf(-logf(f));
}

// ---------------- XLA EmitTanh (clamp +-9, Eigen rational), unfused ---------
__device__ __forceinline__ float xla_tanh(float x) {
  float ax = fabsf(x);
  float xc = fminf(fmaxf(x, -9.0f), 9.0f);
  float x2 = __fmul_rn(xc, xc);
  float p = -2.76076847742355e-16f;
  p = __fadd_rn(__fmul_rn(x2, p),  2.00018790482477e-13f);
  p = __fadd_rn(__fmul_rn(x2, p), -8.60467152213735e-11f);
  p = __fadd_rn(__fmul_rn(x2, p),  5.12229709037114e-08f);
  p = __fadd_rn(__fmul_rn(x2, p),  1.48572235717979e-05f);
  p = __fadd_rn(__fmul_rn(x2, p),  6.37261928875436e-04f);
  p = __fadd_rn(__fmul_rn(x2, p),  4.89352455891786e-03f);
  p = __fmul_rn(xc, p);
  float q = 1.19825839466702e-06f;
  q = __fadd_rn(__fmul_rn(x2, q), 1.18534705686654e-04f);
  q = __fadd_rn(__fmul_rn(x2, q), 2.26843463243900e-03f);
  q = __fadd_rn(__fmul_rn(x2, q), 4.89352518554385e-03f);
  float r = __fdiv_rn(p, q);
  return (ax < 0.0004f) ? x : r;
}

__device__ __forceinline__ float xla_sigmoid(float x) {
  return __fadd_rn(0.5f, __fmul_rn(0.5f, xla_tanh(__fmul_rn(0.5f, x))));
}

// ---------------- weight transposes into ws ---------------------------------
__global__ void transpose_weights(const float* __restrict__ Wdec,
                                  const float* __restrict__ Wih,
                                  const float* __restrict__ Whh,
                                  const float* __restrict__ Wa,
                                  float* __restrict__ ws) {
  int i = blockIdx.x * blockDim.x + threadIdx.x;
  if (i < 16384) {
    int k = i >> 7, j = i & 127;
    ws[i] = Wdec[j * 128 + k];
  } else if (i < 16384 + 65536) {
    int r = i - 16384; int k = r >> 9, g = r & 511;
    ws[16384 + r] = Wih[g * 128 + k];
  } else if (i < 16384 + 131072) {
    int r = i - 81920; int k = r >> 9, g = r & 511;
    ws[81920 + r] = Whh[g * 128 + k];
  } else if (i < 16384 + 131072 + 16384) {
    int r = i - 147456; int k = r >> 7, h = r & 127;
    ws[147456 + r] = Wa[h * 384 + 256 + k];
  }
}

// ---------------- persistent per-batch mega-kernel --------------------------
__global__ __launch_bounds__(NT, 2)
void ptrnet_megakernel(const float* __restrict__ SE,     // (B,H,S)
                       const float* __restrict__ dyn,    // (B,F,S)
                       const float* __restrict__ Wdyn,   // (H,F)
                       const float* __restrict__ bdyn,   // (H)
                       const float* __restrict__ Wa,     // (H,3H)
                       const float* __restrict__ v_att,  // (H)
                       const float* __restrict__ bdec_g, // (H)
                       const float* __restrict__ bih,    // (4H)
                       const float* __restrict__ bhh,    // (4H)
                       const float* __restrict__ ws,     // transposed weights
                       float* __restrict__ out)          // tours(B,S)|logps(B,S)
{
  const int b    = blockIdx.x;
  const int tid  = threadIdx.x;
  const int j8   = tid & 255;   // legacy mapping (precompute phase)
  const int half = tid >> 8;    // legacy mapping (precompute phase)
  const int jd   = tid & 127;   // output index, partitioned GEMVs
  const int pd   = tid >> 7;    // k-partition 0..3, partitioned GEMVs

  const float* WdecT = ws;            // [k][j]
  const float* WihT  = ws + 16384;    // [k][g]
  const float* WhhT  = ws + 81920;    // [k][g]
  const float* Wa3T  = ws + 147456;   // [k][h]

  __shared__ __align__(16) float G_T[SS * GLD];       // 132 KiB
  __shared__ __align__(16) float gxbuf[CHUNK][NT];    // 16 KiB
  __shared__ __align__(16) float xbuf[CHUNK + 1][HH]; // 4.5 KiB (row 0=carry)
  __shared__ __align__(16) float gate[NT];            // GEMV/reduce scratch
  __shared__ __align__(16) float hS[HH], cS[HH], w3h[HH], vS[HH], bdecS[HH];
  __shared__ float sc[SS], kv[SS];
  __shared__ float red[32];
  __shared__ unsigned int fkbuf[CHUNK][2];   // per-step fold_in(key42, t)
  __shared__ unsigned char alist[SS];
  __shared__ int nactS;

  // ---- Precompute G_T[s][h] (identical to r4/r5) ----
  {
    float* Msh  = &xbuf[0][0];
    float* c2   = &xbuf[2][0];
    float* SEst = &gxbuf[0][0];
    if (tid < 256) {
      int h = tid >> 1, f = tid & 1;
      float a = 0.f;
      for (int k = 0; k < HH; ++k)
        a = fmaf(Wa[h * 384 + 128 + k], Wdyn[k * 2 + f], a);
      Msh[tid] = a;
    } else if (tid < 384) {
      int h = tid - 256;
      float a = 0.f;
      for (int k = 0; k < HH; ++k)
        a = fmaf(Wa[h * 384 + 128 + k], bdyn[k], a);
      c2[h] = a;
    }
    __syncthreads();
    {
      float d0 = dyn[(size_t)(b * 2 + 0) * SS + j8];
      float d1 = dyn[(size_t)(b * 2 + 1) * SS + j8];
      const int h0 = half << 6;
      #pragma unroll 4
      for (int i4 = 0; i4 < 16; ++i4) {
        int h = h0 + i4 * 4;
        float4 g;
        g.x = c2[h + 0] + Msh[(h + 0) * 2] * d0 + Msh[(h + 0) * 2 + 1] * d1;
        g.y = c2[h + 1] + Msh[(h + 1) * 2] * d0 + Msh[(h + 1) * 2 + 1] * d1;
        g.z = c2[h + 2] + Msh[(h + 2) * 2] * d0 + Msh[(h + 2) * 2 + 1] * d1;
        g.w = c2[h + 3] + Msh[(h + 3) * 2] * d0 + Msh[(h + 3) * 2 + 1] * d1;
        *(float4*)&G_T[j8 * GLD + h] = g;
      }
    }
    __syncthreads();
    for (int kt = 0; kt < 16; ++kt) {
      #pragma unroll
      for (int r = 0; r < 4; ++r) {
        int idx = r * 512 + tid;
        int kk = idx >> 8, ssx = idx & 255;
        SEst[kk * 256 + ssx] = SE[(size_t)(b * HH + kt * 8 + kk) * SS + ssx];
      }
      __syncthreads();
      float se[8];
      #pragma unroll
      for (int j = 0; j < 8; ++j) se[j] = SEst[j * 256 + j8];
      const int h0 = half << 6;
      for (int i4 = 0; i4 < 16; ++i4) {
        int h = h0 + i4 * 4;
        float4 g = *(const float4*)&G_T[j8 * GLD + h];
        #pragma unroll
        for (int c = 0; c < 4; ++c) {
          const float* war = Wa + (h + c) * 384 + kt * 8;
          float a = 0.f;
          #pragma unroll
          for (int j = 0; j < 8; ++j) a = fmaf(war[j], se[j], a);
          ((float*)&g)[c] += a;
        }
        *(float4*)&G_T[j8 * GLD + h] = g;
      }
      __syncthreads();
    }
  }

  // ---- init rollout state ----
  if (tid < HH) {
    hS[tid] = 0.f; cS[tid] = 0.f;
    xbuf[0][tid] = SE[(size_t)(b * HH + tid) * SS];
    bdecS[tid] = bdec_g[tid];
    vS[tid]    = v_att[tid];
  }
  if (tid < 256) alist[tid] = (unsigned char)tid;
  if (tid == 0) nactS = 256;

  // ---- pin long-lived weight slices (192 floats) ----
  float whh_r[HH];
  #pragma unroll
  for (int k = 0; k < HH; ++k) whh_r[k] = WhhT[k * 512 + tid];
  float wdec_r[32];
  #pragma unroll
  for (int kk = 0; kk < 32; ++kk) wdec_r[kk] = WdecT[(pd * 32 + kk) * HH + jd];
  float wa3_r[32];
  #pragma unroll
  for (int kk = 0; kk < 32; ++kk) wa3_r[kk] = Wa3T[(pd * 32 + kk) * HH + jd];
  __syncthreads();

  // ---- 256 sequential decode steps ----
  for (int t = 0; t < SS; ++t) {
    const int i = t & (CHUNK - 1);

    if (i == 0) {
      // per-step fold_in keys for this chunk (uniform across columns)
      if (tid < CHUNK) {
        unsigned int f0, f1;
        tf2x32(0u, 42u, 0u, (unsigned int)(t + tid), f0, f1);
        fkbuf[tid][0] = f0; fkbuf[tid][1] = f1;
      }
      // chunk prologue: x-chain (identical to r4/r5)
      for (int ii = 0; ii < CHUNK; ++ii) {
        float a = 0.f;
        #pragma unroll
        for (int kk = 0; kk < 32; ++kk)
          a = fmaf(xbuf[ii][pd * 32 + kk], wdec_r[kk], a);
        gate[pd * 128 + jd] = a;
        __syncthreads();
        if (tid < HH) {
          float sum = ((gate[tid] + gate[128 + tid]) + gate[256 + tid]) + gate[384 + tid];
          xbuf[ii + 1][tid] = __fadd_rn(sum, bdecS[tid]);
        }
        __syncthreads();
      }
      if (tid < HH) xbuf[0][tid] = xbuf[CHUNK][tid];
      float bihhh = bih[tid] + bhh[tid];
      #pragma unroll
      for (int pass = 0; pass < 2; ++pass) {
        const float* xA = &xbuf[pass * 4 + 1][0];
        const float* xB = &xbuf[pass * 4 + 2][0];
        const float* xC = &xbuf[pass * 4 + 3][0];
        const float* xD = &xbuf[pass * 4 + 4][0];
        float a0 = bihhh, a1 = bihhh, a2 = bihhh, a3 = bihhh;
        #pragma unroll 8
        for (int k4 = 0; k4 < 32; ++k4) {
          float w0 = WihT[(k4 * 4 + 0) * 512 + tid];
          float w1 = WihT[(k4 * 4 + 1) * 512 + tid];
          float w2 = WihT[(k4 * 4 + 2) * 512 + tid];
          float w3 = WihT[(k4 * 4 + 3) * 512 + tid];
          float4 va = *(const float4*)&xA[k4 * 4];
          float4 vb = *(const float4*)&xB[k4 * 4];
          float4 vc = *(const float4*)&xC[k4 * 4];
          float4 vd = *(const float4*)&xD[k4 * 4];
          a0 = fmaf(va.x, w0, a0); a0 = fmaf(va.y, w1, a0);
          a0 = fmaf(va.z, w2, a0); a0 = fmaf(va.w, w3, a0);
          a1 = fmaf(vb.x, w0, a1); a1 = fmaf(vb.y, w1, a1);
          a1 = fmaf(vb.z, w2, a1); a1 = fmaf(vb.w, w3, a1);
          a2 = fmaf(vc.x, w0, a2); a2 = fmaf(vc.y, w1, a2);
          a2 = fmaf(vc.z, w2, a2); a2 = fmaf(vc.w, w3, a2);
          a3 = fmaf(vd.x, w0, a3); a3 = fmaf(vd.y, w1, a3);
          a3 = fmaf(vd.z, w2, a3); a3 = fmaf(vd.w, w3, a3);
        }
        gxbuf[pass * 4 + 0][tid] = a0;
        gxbuf[pass * 4 + 1][tid] = a1;
        gxbuf[pass * 4 + 2][tid] = a2;
        gxbuf[pass * 4 + 3][tid] = a3;
      }
      __syncthreads();
    }

    // A: gates = gx + h @ Whh^T (k-ascending, identical order)
    {
      float g = gxbuf[i][tid];
      #pragma unroll
      for (int k4 = 0; k4 < HH / 4; ++k4) {
        float4 hv = *(const float4*)&hS[k4 * 4];
        g = fmaf(hv.x, whh_r[k4 * 4 + 0], g);
        g = fmaf(hv.y, whh_r[k4 * 4 + 1], g);
        g = fmaf(hv.z, whh_r[k4 * 4 + 2], g);
        g = fmaf(hv.w, whh_r[k4 * 4 + 3], g);
      }
      gate[tid] = g;
    }
    __syncthreads();
    // C: LSTM cell — lanes 0-31 of waves 0-3 (all 4 SIMDs)
    if (tid < 256 && (tid & 63) < 32) {
      int h = ((tid >> 6) << 5) + (tid & 31);
      float gi = gate[h], gf = gate[128 + h];
      float gg = gate[256 + h], go = gate[384 + h];
      float c_new = __fadd_rn(__fmul_rn(xla_sigmoid(gf), cS[h]),
                              __fmul_rn(xla_sigmoid(gi), xla_tanh(gg)));
      float h_new = __fmul_rn(xla_sigmoid(go), xla_tanh(c_new));
      cS[h] = c_new; hS[h] = h_new;
    }
    __syncthreads();

    if (t == 0) {
      if (tid == 0) {
#if TOURS_AS_INT
        ((int*)out)[b * SS + 0] = 0;
#else
        out[b * SS + 0] = 0.0f;
#endif
        out[BB * SS + b * SS + 0] = 0.0f;
        alist[0] = alist[255];
        nactS = 255;
      }
      continue;
    }

    // D: w3h = Wa3 @ h (partitioned 4x32; identical order)
    {
      float a = 0.f;
      #pragma unroll
      for (int kk = 0; kk < 32; ++kk)
        a = fmaf(hS[pd * 32 + kk], wa3_r[kk], a);
      gate[pd * 128 + jd] = a;
    }
    __syncthreads();
    if (tid < HH)
      w3h[tid] = ((gate[tid] + gate[128 + tid]) + gate[256 + tid]) + gate[384 + tid];
    __syncthreads();

    const int nact = nactS;

    // E: partial scores — WAVE-STRIDED mapping: column j = pos*8 + wv is
    // handled by wave wv, lane-pair pos. All 8 waves (4 SIMDs) stay busy for
    // any nact>=8, balanced within 1 column. Per-(column,half) arithmetic
    // identical to r4/r5.
    {
      const int wv    = tid >> 6;        // 0..7
      const int lane  = tid & 63;
      const int pos   = lane >> 1;       // 0..31
      const int halfe = lane & 1;
      const int j     = pos * 8 + wv;    // column-list position (bijective)
      if (j < nact) {
        const int s = alist[j];
        const float* grow = &G_T[s * GLD];
        float acc = 0.f;
        const int h0 = halfe << 6;
        #pragma unroll 4
        for (int i4 = 0; i4 < 16; ++i4) {
          int h = h0 + i4 * 4;
          float4 gv = *(const float4*)&grow[h];
          float4 wv4 = *(const float4*)&w3h[h];
          float4 vv = *(const float4*)&vS[h];
          float z0 = __fadd_rn(gv.x, wv4.x);
          float z1 = __fadd_rn(gv.y, wv4.y);
          float z2 = __fadd_rn(gv.z, wv4.z);
          float z3 = __fadd_rn(gv.w, wv4.w);
          acc = fmaf(vv.x, xla_tanh(z0), acc);
          acc = fmaf(vv.y, xla_tanh(z1), acc);
          acc = fmaf(vv.z, xla_tanh(z2), acc);
          acc = fmaf(vv.w, xla_tanh(z3), acc);
        }
        if (halfe == 0) sc[j] = acc; else kv[j] = acc;
      }
    }
    __syncthreads();

    // F+G1: logits + gumbel keys + argmax partials — WAVE-STRIDED over
    // waves 0-3: column j = lane*4 + wv. Max-reduce is order-independent
    // (deterministic tie-break on smallest s).
    float flogit = NEG_INF;
    int   myj    = 0x7FFFFFFF;
    if (tid < 256) {
      const int wv   = tid >> 6;       // 0..3
      const int lane = tid & 63;
      const int j    = lane * 4 + wv;  // column-list position (bijective)
      myj = j;
      float val, mx; int sidx;
      if (j < nact) {
        const int s = alist[j];
        flogit = __fadd_rn(sc[j], kv[j]);   // same order: sc+kv
        unsigned int o0, o1, bits;
#if JAX_PARTITIONABLE
        tf2x32(fkbuf[i][0], fkbuf[i][1], 0u, (unsigned int)(b * 256 + s), o0, o1);
        bits = o0 ^ o1;
#else
        int jj = b * 256 + s;
        if (jj < 32768) { tf2x32(fkbuf[i][0], fkbuf[i][1], (unsigned)jj, (unsigned)(jj + 32768), o0, o1); bits = o0; }
        else            { tf2x32(fkbuf[i][0], fkbuf[i][1], (unsigned)(jj - 32768), (unsigned)jj, o0, o1); bits = o1; }
#endif
        float gum = gumbel_from_bits(bits);
        val = __fadd_rn(flogit, gum);
        mx = flogit; sidx = s;
      } else {
        val = -INFINITY; mx = -INFINITY; sidx = 0x7FFFFFFF;
      }
      int jwin = myj;
      #pragma unroll
      for (int off = 1; off < 64; off <<= 1) {
        float ov = __shfl_xor(val, off);
        int   oi = __shfl_xor(sidx, off);
        int   oj = __shfl_xor(jwin, off);
        float om = __shfl_xor(mx, off);
        if (ov > val || (ov == val && oi < sidx)) { val = ov; sidx = oi; jwin = oj; }
        mx = fmaxf(mx, om);
      }
      if ((tid & 63) == 0) {
        red[wv * 4 + 0] = val;
        red[wv * 4 + 1] = __int_as_float(sidx);
        red[wv * 4 + 2] = __int_as_float(jwin);
        red[wv * 4 + 3] = mx;
      }
    }
    __syncthreads();

    // G-final (all tid<256 redundantly; order-independent max) + G2 exp-sum
    int   bj = -1, bs = 0;
    float bm = 0.f;
    if (tid < 256) {
      float bv = red[0]; bs = __float_as_int(red[1]);
      bj = __float_as_int(red[2]); bm = red[3];
      #pragma unroll
      for (int w = 1; w < 4; ++w) {
        float ov = red[w * 4], om = red[w * 4 + 3];
        int os = __float_as_int(red[w * 4 + 1]);
        int oj = __float_as_int(red[w * 4 + 2]);
        if (ov > bv || (ov == bv && os < bs)) { bv = ov; bs = os; bj = oj; }
        bm = fmaxf(bm, om);
      }
      float e = (myj < nact) ? expf(__fsub_rn(flogit, bm)) : 0.f;
      #pragma unroll
      for (int off = 1; off < 64; off <<= 1) e += __shfl_xor(e, off);
      if ((tid & 63) == 0) red[20 + (tid >> 6)] = e;
    }
    __syncthreads();

    // H: winner thread (unique: myj == bj) writes outputs + swap-remove
    if (tid < 256 && myj == bj) {
      float tot = ((red[20] + red[21]) + red[22]) + red[23];
      float logp = __fsub_rn(__fsub_rn(flogit, bm), logf(tot));
#if TOURS_AS_INT
      ((int*)out)[b * SS + t] = bs;
#else
      out[b * SS + t] = (float)bs;
#endif
      out[BB * SS + b * SS + t] = logp;
      alist[bj] = alist[nact - 1];
      nactS = nact - 1;
    }
    // next reads of alist/nactS/red occur >=2 barriers later (A/C/D barriers)
  }
}

extern "C" void kernel_launch(void* const* d_in, const int* in_sizes, int n_in,
                              void* d_out, int out_size, void* d_ws, size_t ws_size,
                              hipStream_t stream) {
  (void)in_sizes; (void)n_in; (void)out_size; (void)ws_size;
  const float* SE      = (const float*)d_in[1];
  const float* dynamic = (const float*)d_in[2];
  const float* Wdyn    = (const float*)d_in[3];
  const float* bdyn    = (const float*)d_in[4];
  const float* Wdec    = (const float*)d_in[5];
  const float* bdec    = (const float*)d_in[6];
  const float* Wih     = (const float*)d_in[7];
  const float* Whh     = (const float*)d_in[8];
  const float* bih     = (const float*)d_in[9];
  const float* bhh     = (const float*)d_in[10];
  const float* Wa      = (const float*)d_in[11];
  const float* v_att   = (const float*)d_in[12];
  float* out = (float*)d_out;
  float* ws  = (float*)d_ws;   // 163840 floats = 640 KiB

  transpose_weights<<<640, 256, 0, stream>>>(Wdec, Wih, Whh, Wa, ws);
  ptrnet_megakernel<<<BB, NT, 0, stream>>>(SE, dynamic, Wdyn, bdyn, Wa, v_att,
                                           bdec, bih, bhh, ws, out);
}